// Round 1
// 1297.521 us; speedup vs baseline: 1.2390x; 1.2390x over previous
//
#include <hip/hip_runtime.h>
#include <math.h>

#define TT 1024
#define VV 32000
#define EE 1024
#define NH 16
#define NKVH 4
#define DHEAD 64
#define QKVN 1536    // E + 2*NKVH*DHEAD
#define FF 4096
#define LEPS 1e-5f

typedef __attribute__((ext_vector_type(8))) short short8;
typedef __attribute__((ext_vector_type(4))) float floatx4;

__device__ __forceinline__ ushort f2bf(float f) {
    unsigned x = __float_as_uint(f);
    unsigned r = (x + 0x7fffu + ((x >> 16) & 1u)) >> 16;
    return (ushort)r;
}
__device__ __forceinline__ float bf2f(ushort u) {
    return __uint_as_float(((unsigned)u) << 16);
}

// ---------------- block reduction helpers (blockDim.x == 256) ----------------
__device__ __forceinline__ float block_reduce_sum(float v, float* red) {
    int tid = threadIdx.x;
    red[tid] = v; __syncthreads();
    for (int off = 128; off > 0; off >>= 1) {
        if (tid < off) red[tid] += red[tid + off];
        __syncthreads();
    }
    float r = red[0];
    __syncthreads();
    return r;
}
__device__ __forceinline__ float block_reduce_max(float v, float* red) {
    int tid = threadIdx.x;
    red[tid] = v; __syncthreads();
    for (int off = 128; off > 0; off >>= 1) {
        if (tid < off) red[tid] = fmaxf(red[tid], red[tid + off]);
        __syncthreads();
    }
    float r = red[0];
    __syncthreads();
    return r;
}

// ---------------- prep: fp32 -> bf16 flat convert (embed) ----------------
__global__ __launch_bounds__(256) void convert_bf16_kernel(const float* __restrict__ src,
                                                           ushort* __restrict__ dst, long n4) {
    long i = (long)blockIdx.x * 256 + threadIdx.x;
    if (i >= n4) return;
    float4 f = ((const float4*)src)[i];
    ushort u[4] = { f2bf(f.x), f2bf(f.y), f2bf(f.z), f2bf(f.w) };
    ((uint2*)dst)[i] = *(uint2*)u;
}

// ---------------- prep: W (K x N fp32) -> dst (N x K bf16) ----------------
__global__ __launch_bounds__(256) void transpose_bf16_kernel(const float* __restrict__ W,
                                                             ushort* __restrict__ dst,
                                                             int N, int K) {
    __shared__ float tile[32][33];
    int n0 = blockIdx.x * 32, k0 = blockIdx.y * 32;
    int tx = threadIdx.x & 31, ty = threadIdx.x >> 5;
    for (int i = ty; i < 32; i += 8) tile[i][tx] = W[(long)(k0 + i) * N + n0 + tx];
    __syncthreads();
    for (int i = ty; i < 32; i += 8)
        dst[(long)(n0 + i) * K + k0 + tx] = f2bf(tile[tx][i]);
}

// ---------------- embedding gather ----------------
__global__ __launch_bounds__(256) void gather_kernel(const float* __restrict__ embed,
                                                     const int* __restrict__ idx,
                                                     float* __restrict__ x) {
    int t = blockIdx.x;
    long r = idx[t];
    const float4* src = (const float4*)(embed + r * EE);
    float4* dst = (float4*)(x + (long)t * EE);
    for (int i = threadIdx.x; i < EE / 4; i += 256) dst[i] = src[i];
}

// ---------------- layernorm (one block per row) -> bf16 out ----------------
__global__ __launch_bounds__(256) void ln_kernel(const float* __restrict__ x,
                                                 const float* __restrict__ g,
                                                 const float* __restrict__ b,
                                                 ushort* __restrict__ out) {
    __shared__ float red[256];
    int t = blockIdx.x;
    const float* xr = x + (long)t * EE;
    float s = 0.f;
    for (int i = threadIdx.x; i < EE; i += 256) s += xr[i];
    float mu = block_reduce_sum(s, red) * (1.f / EE);
    float vs = 0.f;
    for (int i = threadIdx.x; i < EE; i += 256) { float d = xr[i] - mu; vs += d * d; }
    float var = block_reduce_sum(vs, red) * (1.f / EE);
    float rstd = rsqrtf(var + LEPS);
    ushort* orow = out + (long)t * EE;
    for (int i = threadIdx.x; i < EE; i += 256)
        orow[i] = f2bf((xr[i] - mu) * rstd * g[i] + b[i]);
}

// ---------------- RoPE (first 32 dims of each head), in-place bf16 ----------
__global__ __launch_bounds__(256) void rope_kernel(ushort* __restrict__ q, int nheads, int rowstride) {
    int idx = blockIdx.x * 256 + threadIdx.x;
    int total = TT * nheads * 16;
    if (idx >= total) return;
    int i = idx & 15;
    int h = (idx >> 4) % nheads;
    int t = idx / (16 * nheads);
    float theta = expf(-(float)i * (9.210340371976184f / 16.f));
    float ang = (float)t * theta;
    float c = cosf(ang), s = sinf(ang);
    ushort* p = q + (long)t * rowstride + h * DHEAD;
    float a = bf2f(p[i]), bb = bf2f(p[i + 16]);
    p[i]      = f2bf(a * c - bb * s);
    p[i + 16] = f2bf(bb * c + a * s);
}

// ---------------- bf16 MFMA GEMM: C[M,N] = A[M,K] @ Bt[N,K]^T ----------------
// Grid: x = (M/128)*(N/128) linear (XCD-chunked swizzle, row-fastest so the 8
// row-tiles sharing one B panel land on the SAME XCD's L2), y = split-K slices.
// Split-K (gridDim.y>1) requires ADD=false, OUTBF=false; each slice writes its
// fp32 partial at Cv + slice*M*N; reduce_add_kernel folds them into x.
template<bool GELU_ACT, bool ADD, bool OUTBF>
__global__ __launch_bounds__(256) void gemm_bf16(const ushort* __restrict__ A,
                                                 const ushort* __restrict__ B,
                                                 void* __restrict__ Cv,
                                                 int M, int N, int K) {
    __shared__ char lds[16384];   // A tile 8KB @0, B tile 8KB @8192
    const int tid = threadIdx.x;
    const int lane = tid & 63;
    const int w = tid >> 6;

    // --- XCD-chunked bijective swizzle (m204), row-fastest tile order ---
    const int nwg = gridDim.x;
    const int lin = blockIdx.x;
    const int q8 = nwg >> 3, r8 = nwg & 7;
    const int xcd = lin & 7, loc = lin >> 3;
    const int wg = (xcd < r8 ? xcd * (q8 + 1) : r8 * (q8 + 1) + (xcd - r8) * q8) + loc;
    const int MB = M >> 7;
    const int row0 = (wg % MB) * 128;
    const int col0 = (wg / MB) * 128;

    // --- split-K slice ---
    const int nsl = gridDim.y;
    const int kslice = K / nsl;                 // divisibility guaranteed by host
    const long koff = (long)blockIdx.y * kslice;

    const char* ga[2]; const char* gb[2];
    char* la[2]; char* lb[2];
    #pragma unroll
    for (int r = 0; r < 2; ++r) {
        int c = r * 256 + tid;
        ga[r] = (const char*)A + ((long)(row0 + (c >> 2)) * K + koff) * 2 + (c & 3) * 16;
        gb[r] = (const char*)B + ((long)(col0 + (c >> 2)) * K + koff) * 2 + (c & 3) * 16;
        int wc = r * 256 + w * 64;
        la[r] = lds + wc * 16;
        lb[r] = lds + 8192 + wc * 16;
    }

    floatx4 acc[4][4];
    #pragma unroll
    for (int i = 0; i < 4; ++i)
        #pragma unroll
        for (int j = 0; j < 4; ++j) acc[i][j] = {0.f, 0.f, 0.f, 0.f};

    const int mbase = (w >> 1) * 64;
    const int nbase = (w & 1) * 64;
    const int lr = lane & 15;
    const int ko = (lane >> 4) * 16;

    for (int k0 = 0; k0 < kslice; k0 += 32) {
        #pragma unroll
        for (int r = 0; r < 2; ++r) {
            __builtin_amdgcn_global_load_lds(
                (const __attribute__((address_space(1))) void*)ga[r],
                (__attribute__((address_space(3))) void*)la[r], 16, 0, 0);
            __builtin_amdgcn_global_load_lds(
                (const __attribute__((address_space(1))) void*)gb[r],
                (__attribute__((address_space(3))) void*)lb[r], 16, 0, 0);
            ga[r] += 64; gb[r] += 64;
        }
        __syncthreads();
        short8 af[4], bfr[4];
        #pragma unroll
        for (int i = 0; i < 4; ++i)
            af[i] = *(const short8*)(lds + (mbase + i * 16 + lr) * 64 + ko);
        #pragma unroll
        for (int j = 0; j < 4; ++j)
            bfr[j] = *(const short8*)(lds + 8192 + (nbase + j * 16 + lr) * 64 + ko);
        #pragma unroll
        for (int i = 0; i < 4; ++i)
            #pragma unroll
            for (int j = 0; j < 4; ++j)
                acc[i][j] = __builtin_amdgcn_mfma_f32_16x16x32_bf16(af[i], bfr[j], acc[i][j], 0, 0, 0);
        __syncthreads();
    }

    const int orow = (lane >> 4) * 4;
    const int ocol = lane & 15;
    #pragma unroll
    for (int i = 0; i < 4; ++i) {
        #pragma unroll
        for (int j = 0; j < 4; ++j) {
            #pragma unroll
            for (int r = 0; r < 4; ++r) {
                long off = (long)(row0 + mbase + i * 16 + orow + r) * N
                         + (col0 + nbase + j * 16 + ocol);
                float v = acc[i][j][r];
                if (GELU_ACT) v = 0.5f * v * (1.f + erff(v * 0.70710678118654752f));
                if (OUTBF) {
                    ((ushort*)Cv)[off] = f2bf(v);
                } else {
                    float* C = (float*)Cv + (long)blockIdx.y * (long)M * N;
                    if (ADD) C[off] += v; else C[off] = v;
                }
            }
        }
    }
}

// ---------------- split-K reduce: x[i] += sum_s part[s][i] (float4) ----------
__global__ __launch_bounds__(256) void reduce_add_kernel(const float* __restrict__ part,
                                                         float* __restrict__ x,
                                                         long n4, int SK) {
    long i = (long)blockIdx.x * 256 + threadIdx.x;
    if (i >= n4) return;
    float4 s = ((const float4*)part)[i];
    for (int k = 1; k < SK; ++k) {
        float4 t = ((const float4*)part)[i + (long)k * n4];
        s.x += t.x; s.y += t.y; s.z += t.z; s.w += t.w;
    }
    float4 d = ((float4*)x)[i];
    d.x += s.x; d.y += s.y; d.z += s.z; d.w += s.w;
    ((float4*)x)[i] = d;
}

// ---------------- scores = Q @ K^T per head (causal-skip), fp32 out ---------
// A = qkv rows (stride QKVN) at head offset; B = qkv rows at k offset.
__global__ __launch_bounds__(256) void scores_gemm(const ushort* __restrict__ qkv,
                                                   float* __restrict__ scores) {
    __shared__ char lds[16384];
    const int tid = threadIdx.x;
    const int lane = tid & 63;
    const int w = tid >> 6;
    const int col0 = blockIdx.x * 128, row0 = blockIdx.y * 128, h = blockIdx.z;
    if (col0 > row0) return;   // fully-masked causal tile

    const ushort* A = qkv + h * DHEAD;
    const ushort* B = qkv + EE + (h >> 2) * DHEAD;

    const char* ga[2]; const char* gb[2];
    char* la[2]; char* lb[2];
    #pragma unroll
    for (int r = 0; r < 2; ++r) {
        int c = r * 256 + tid;
        ga[r] = (const char*)A + (long)(row0 + (c >> 2)) * QKVN * 2 + (c & 3) * 16;
        gb[r] = (const char*)B + (long)(col0 + (c >> 2)) * QKVN * 2 + (c & 3) * 16;
        int wc = r * 256 + w * 64;
        la[r] = lds + wc * 16;
        lb[r] = lds + 8192 + wc * 16;
    }

    floatx4 acc[4][4];
    #pragma unroll
    for (int i = 0; i < 4; ++i)
        #pragma unroll
        for (int j = 0; j < 4; ++j) acc[i][j] = {0.f, 0.f, 0.f, 0.f};

    const int mbase = (w >> 1) * 64;
    const int nbase = (w & 1) * 64;
    const int lr = lane & 15;
    const int ko = (lane >> 4) * 16;

    for (int k0 = 0; k0 < DHEAD; k0 += 32) {
        #pragma unroll
        for (int r = 0; r < 2; ++r) {
            __builtin_amdgcn_global_load_lds(
                (const __attribute__((address_space(1))) void*)ga[r],
                (__attribute__((address_space(3))) void*)la[r], 16, 0, 0);
            __builtin_amdgcn_global_load_lds(
                (const __attribute__((address_space(1))) void*)gb[r],
                (__attribute__((address_space(3))) void*)lb[r], 16, 0, 0);
            ga[r] += 64; gb[r] += 64;
        }
        __syncthreads();
        short8 af[4], bfr[4];
        #pragma unroll
        for (int i = 0; i < 4; ++i)
            af[i] = *(const short8*)(lds + (mbase + i * 16 + lr) * 64 + ko);
        #pragma unroll
        for (int j = 0; j < 4; ++j)
            bfr[j] = *(const short8*)(lds + 8192 + (nbase + j * 16 + lr) * 64 + ko);
        #pragma unroll
        for (int i = 0; i < 4; ++i)
            #pragma unroll
            for (int j = 0; j < 4; ++j)
                acc[i][j] = __builtin_amdgcn_mfma_f32_16x16x32_bf16(af[i], bfr[j], acc[i][j], 0, 0, 0);
        __syncthreads();
    }

    float* C = scores + (long)h * TT * TT;
    const int orow = (lane >> 4) * 4;
    const int ocol = lane & 15;
    #pragma unroll
    for (int i = 0; i < 4; ++i)
        #pragma unroll
        for (int j = 0; j < 4; ++j)
            #pragma unroll
            for (int r = 0; r < 4; ++r)
                C[(long)(row0 + mbase + i * 16 + orow + r) * TT
                  + (col0 + nbase + j * 16 + ocol)] = acc[i][j][r];
}

// ---------------- softmax + gate threshold; bf16 P written in place ---------
// Reads fp32 row [0..t] into LDS, writes bf16 P (stride-2048-ushort rows).
__global__ __launch_bounds__(256) void softmax_gate_kernel(float* __restrict__ scores,
                                                           const float* __restrict__ gate) {
    __shared__ float sc[TT];
    __shared__ float red[256];
    int h = blockIdx.x;
    int t = blockIdx.y;
    int tid = threadIdx.x;
    float* row = scores + (long)h * TT * TT + (long)t * TT;

    float lmax = -INFINITY;
    for (int s = tid; s <= t; s += 256) {
        float v = row[s] * 0.125f;   // 1/sqrt(DH)
        sc[s] = v;
        lmax = fmaxf(lmax, v);
    }
    float mx = block_reduce_max(lmax, red);
    float lsum = 0.f;
    for (int s = tid; s <= t; s += 256) {
        float e = expf(sc[s] - mx);
        sc[s] = e;
        lsum += e;
    }
    float sum = block_reduce_sum(lsum, red);   // barrier: all fp32 reads done
    float inv = 1.f / sum;
    float thr = 1.f / (1.f + expf(-gate[h]));

    ushort* prow = (ushort*)row;               // alias — safe post-barrier
    for (int s = tid; s < TT; s += 256) {
        float p = (s <= t) ? sc[s] * inv : 0.f;
        p = (p >= thr) ? p : 0.f;
        prow[s] = f2bf(p);
    }
}

// ---------------- V^T: qkv v-part [TT,256] -> VT [256,TT] bf16 --------------
__global__ __launch_bounds__(256) void vtrans_kernel(const ushort* __restrict__ qkv,
                                                     ushort* __restrict__ VT) {
    __shared__ ushort tile[32][33];
    int s0 = blockIdx.x * 32, d0 = blockIdx.y * 32;
    int tx = threadIdx.x & 31, ty = threadIdx.x >> 5;
    for (int i = ty; i < 32; i += 8)
        tile[i][tx] = qkv[(long)(s0 + i) * QKVN + (EE + NKVH * DHEAD) + d0 + tx];
    __syncthreads();
    for (int i = ty; i < 32; i += 8)
        VT[(long)(d0 + i) * TT + s0 + tx] = tile[tx][i];
}

// ---------------- y = P @ V per head: tile 128x64, bf16 out -----------------
__global__ __launch_bounds__(256) void pv_gemm(const float* __restrict__ scores,
                                               const ushort* __restrict__ VT,
                                               ushort* __restrict__ y) {
    __shared__ char lds[12288];   // A 8KB @0, B 4KB @8192
    const int tid = threadIdx.x;
    const int lane = tid & 63;
    const int w = tid >> 6;
    const int row0 = blockIdx.x * 128, h = blockIdx.y;

    const char* Pb = (const char*)(scores + (long)h * TT * TT);  // P rows: 4096B stride, 2048B used
    const char* Bv = (const char*)(VT + (long)(h >> 2) * DHEAD * TT);

    const char* ga[2]; char* la[2];
    #pragma unroll
    for (int r = 0; r < 2; ++r) {
        int c = r * 256 + tid;
        ga[r] = Pb + (long)(row0 + (c >> 2)) * 4096 + (c & 3) * 16;
        la[r] = lds + (r * 256 + w * 64) * 16;
    }
    const char* gb = Bv + (long)(tid >> 2) * 2048 + (tid & 3) * 16;
    char* lb = lds + 8192 + (w * 64) * 16;

    floatx4 acc[2][4];
    #pragma unroll
    for (int i = 0; i < 2; ++i)
        #pragma unroll
        for (int j = 0; j < 4; ++j) acc[i][j] = {0.f, 0.f, 0.f, 0.f};

    const int mbase = w * 32;
    const int lr = lane & 15;
    const int ko = (lane >> 4) * 16;

    for (int k0 = 0; k0 < TT; k0 += 32) {
        #pragma unroll
        for (int r = 0; r < 2; ++r) {
            __builtin_amdgcn_global_load_lds(
                (const __attribute__((address_space(1))) void*)ga[r],
                (__attribute__((address_space(3))) void*)la[r], 16, 0, 0);
            ga[r] += 64;
        }
        __builtin_amdgcn_global_load_lds(
            (const __attribute__((address_space(1))) void*)gb,
            (__attribute__((address_space(3))) void*)lb, 16, 0, 0);
        gb += 64;
        __syncthreads();
        short8 af[2], bfr[4];
        #pragma unroll
        for (int i = 0; i < 2; ++i)
            af[i] = *(const short8*)(lds + (mbase + i * 16 + lr) * 64 + ko);
        #pragma unroll
        for (int j = 0; j < 4; ++j)
            bfr[j] = *(const short8*)(lds + 8192 + (j * 16 + lr) * 64 + ko);
        #pragma unroll
        for (int i = 0; i < 2; ++i)
            #pragma unroll
            for (int j = 0; j < 4; ++j)
                acc[i][j] = __builtin_amdgcn_mfma_f32_16x16x32_bf16(af[i], bfr[j], acc[i][j], 0, 0, 0);
        __syncthreads();
    }

    const int orow = (lane >> 4) * 4;
    const int ocol = lane & 15;
    #pragma unroll
    for (int i = 0; i < 2; ++i)
        #pragma unroll
        for (int j = 0; j < 4; ++j)
            #pragma unroll
            for (int r = 0; r < 4; ++r)
                y[(long)(row0 + mbase + i * 16 + orow + r) * EE
                  + h * DHEAD + j * 16 + ocol] = f2bf(acc[i][j][r]);
}

// ---------------- loss ----------------
__global__ __launch_bounds__(256) void row_loss_kernel(const float* __restrict__ logits,
                                                       const int* __restrict__ targets,
                                                       float* __restrict__ row_loss) {
    __shared__ float red[256];
    int t = blockIdx.x;
    const float* lr = logits + (long)t * VV;
    float lmax = -INFINITY;
    for (int i = threadIdx.x; i < VV; i += 256) lmax = fmaxf(lmax, lr[i]);
    float mx = block_reduce_max(lmax, red);
    float ls = 0.f;
    for (int i = threadIdx.x; i < VV; i += 256) ls += expf(lr[i] - mx);
    float sum = block_reduce_sum(ls, red);
    if (threadIdx.x == 0)
        row_loss[t] = logf(sum) + mx - lr[targets[t]];
}

__global__ __launch_bounds__(256) void final_loss_kernel(const float* __restrict__ row_loss,
                                                         float* __restrict__ out) {
    __shared__ float red[256];
    float s = 0.f;
    for (int i = threadIdx.x; i < TT; i += 256) s += row_loss[i];
    float tot = block_reduce_sum(s, red);
    if (threadIdx.x == 0) out[0] = tot * (1.f / TT);
}

// ---------------- host orchestration ----------------
extern "C" void kernel_launch(void* const* d_in, const int* in_sizes, int n_in,
                              void* d_out, int out_size, void* d_ws, size_t ws_size,
                              hipStream_t stream) {
    const float* embed = (const float*)d_in[0];
    const float* ln1_g = (const float*)d_in[1];
    const float* ln1_b = (const float*)d_in[2];
    const float* Wq    = (const float*)d_in[3];
    const float* Wk    = (const float*)d_in[4];
    const float* Wv    = (const float*)d_in[5];
    const float* Wo    = (const float*)d_in[6];
    const float* gate  = (const float*)d_in[7];
    const float* ln2_g = (const float*)d_in[8];
    const float* ln2_b = (const float*)d_in[9];
    const float* W1    = (const float*)d_in[10];
    const float* W2    = (const float*)d_in[11];
    const float* lnf_g = (const float*)d_in[12];
    const float* lnf_b = (const float*)d_in[13];
    const int*   idx   = (const int*)d_in[14];
    const int*   tgt   = (const int*)d_in[15];
    float* out = (float*)d_out;

    char* p = (char*)d_ws;
    float*  x      = (float*)p;  p += (long)TT * EE * 4;
    ushort* xn     = (ushort*)p; p += (long)TT * EE * 2;
    ushort* qkvb   = (ushort*)p; p += (long)TT * QKVN * 2;
    ushort* y      = (ushort*)p; p += (long)TT * EE * 2;
    ushort* h1     = (ushort*)p; p += (long)TT * FF * 2;
    float*  rls    = (float*)p;  p += (long)TT * 4;
    ushort* VT     = (ushort*)p; p += (long)NKVH * DHEAD * TT * 2;
    float*  scores = (float*)p;  p += (long)NH * TT * TT * 4;
    ushort* wqkvT  = (ushort*)p; p += (long)2 * QKVN * EE * 2;
    ushort* woT    = (ushort*)p; p += (long)2 * EE * EE * 2;
    ushort* w1T    = (ushort*)p; p += (long)2 * FF * EE * 2;
    ushort* w2T    = (ushort*)p; p += (long)2 * EE * FF * 2;
    ushort* embB   = (ushort*)p; p += (long)VV * EE * 2;

    // split-K partial scratch: alias the scores buffer (dead during Wo / FF2)
    float* gpart = scores;

    // ---- prep: bf16 conversions / transposes ----
    convert_bf16_kernel<<<((long)VV * EE / 4 + 255) / 256, 256, 0, stream>>>(embed, embB, (long)VV * EE / 4);
    for (int l = 0; l < 2; ++l) {
        transpose_bf16_kernel<<<dim3(EE / 32, EE / 32), 256, 0, stream>>>(
            Wq + (long)l * EE * EE, wqkvT + (long)l * QKVN * EE, EE, EE);
        transpose_bf16_kernel<<<dim3(NKVH * DHEAD / 32, EE / 32), 256, 0, stream>>>(
            Wk + (long)l * EE * NKVH * DHEAD, wqkvT + (long)l * QKVN * EE + (long)EE * EE, NKVH * DHEAD, EE);
        transpose_bf16_kernel<<<dim3(NKVH * DHEAD / 32, EE / 32), 256, 0, stream>>>(
            Wv + (long)l * EE * NKVH * DHEAD, wqkvT + (long)l * QKVN * EE + (long)(EE + NKVH * DHEAD) * EE, NKVH * DHEAD, EE);
        transpose_bf16_kernel<<<dim3(EE / 32, EE / 32), 256, 0, stream>>>(
            Wo + (long)l * EE * EE, woT + (long)l * EE * EE, EE, EE);
        transpose_bf16_kernel<<<dim3(FF / 32, EE / 32), 256, 0, stream>>>(
            W1 + (long)l * EE * FF, w1T + (long)l * FF * EE, FF, EE);
        transpose_bf16_kernel<<<dim3(EE / 32, FF / 32), 256, 0, stream>>>(
            W2 + (long)l * FF * EE, w2T + (long)l * EE * FF, EE, FF);
    }

    gather_kernel<<<TT, 256, 0, stream>>>(embed, idx, x);

    for (int r = 0; r < 2; ++r) {
        for (int l = 0; l < 2; ++l) {
            ln_kernel<<<TT, 256, 0, stream>>>(x, ln1_g + l * EE, ln1_b + l * EE, xn);
            gemm_bf16<false, false, true><<<dim3((TT / 128) * (QKVN / 128)), 256, 0, stream>>>(
                xn, wqkvT + (long)l * QKVN * EE, qkvb, TT, QKVN, EE);
            rope_kernel<<<(TT * NH * 16 + 255) / 256, 256, 0, stream>>>(qkvb, NH, QKVN);
            rope_kernel<<<(TT * NKVH * 16 + 255) / 256, 256, 0, stream>>>(qkvb + EE, NKVH, QKVN);
            vtrans_kernel<<<dim3(TT / 32, NKVH * DHEAD / 32), 256, 0, stream>>>(qkvb, VT);
            scores_gemm<<<dim3(TT / 128, TT / 128, NH), 256, 0, stream>>>(qkvb, scores);
            softmax_gate_kernel<<<dim3(NH, TT), 256, 0, stream>>>(scores, gate + l * NH);
            pv_gemm<<<dim3(TT / 128, NH), 256, 0, stream>>>(scores, VT, y);

            // Wo: split-K=2 into fp32 partials (scores scratch), then reduce-add into x
            gemm_bf16<false, false, false><<<dim3((TT / 128) * (EE / 128), 2), 256, 0, stream>>>(
                y, woT + (long)l * EE * EE, gpart, TT, EE, EE);
            reduce_add_kernel<<<(TT * EE / 4 + 255) / 256, 256, 0, stream>>>(
                gpart, x, (long)TT * EE / 4, 2);

            ln_kernel<<<TT, 256, 0, stream>>>(x, ln2_g + l * EE, ln2_b + l * EE, xn);
            gemm_bf16<true, false, true><<<dim3((TT / 128) * (FF / 128)), 256, 0, stream>>>(
                xn, w1T + (long)l * FF * EE, h1, TT, FF, EE);

            // FF2: split-K=4 into fp32 partials, then reduce-add into x
            gemm_bf16<false, false, false><<<dim3((TT / 128) * (EE / 128), 4), 256, 0, stream>>>(
                h1, w2T + (long)l * EE * FF, gpart, TT, EE, FF);
            reduce_add_kernel<<<(TT * EE / 4 + 255) / 256, 256, 0, stream>>>(
                gpart, x, (long)TT * EE / 4, 4);
        }
    }

    ln_kernel<<<TT, 256, 0, stream>>>(x, lnf_g, lnf_b, xn);
    gemm_bf16<false, false, false><<<dim3((TT / 128) * (VV / 128)), 256, 0, stream>>>(
        xn, embB, out, TT, VV, EE);

    row_loss_kernel<<<TT, 256, 0, stream>>>(out, tgt, rls);
    final_loss_kernel<<<1, 256, 0, stream>>>(rls, out + (long)TT * VV);
}

// Round 3
// 1186.372 us; speedup vs baseline: 1.3551x; 1.0937x over previous
//
#include <hip/hip_runtime.h>
#include <math.h>

#define TT 1024
#define VV 32000
#define EE 1024
#define NH 16
#define NKVH 4
#define DHEAD 64
#define QKVN 1536    // E + 2*NKVH*DHEAD
#define FF 4096
#define LEPS 1e-5f

typedef __attribute__((ext_vector_type(8))) short short8;
typedef __attribute__((ext_vector_type(4))) float floatx4;

__device__ __forceinline__ ushort f2bf(float f) {
    unsigned x = __float_as_uint(f);
    unsigned r = (x + 0x7fffu + ((x >> 16) & 1u)) >> 16;
    return (ushort)r;
}
__device__ __forceinline__ float bf2f(ushort u) {
    return __uint_as_float(((unsigned)u) << 16);
}

// ---------------- block reduction helpers (blockDim.x == 256) ----------------
__device__ __forceinline__ float block_reduce_sum(float v, float* red) {
    int tid = threadIdx.x;
    red[tid] = v; __syncthreads();
    for (int off = 128; off > 0; off >>= 1) {
        if (tid < off) red[tid] += red[tid + off];
        __syncthreads();
    }
    float r = red[0];
    __syncthreads();
    return r;
}
__device__ __forceinline__ float block_reduce_max(float v, float* red) {
    int tid = threadIdx.x;
    red[tid] = v; __syncthreads();
    for (int off = 128; off > 0; off >>= 1) {
        if (tid < off) red[tid] = fmaxf(red[tid], red[tid + off]);
        __syncthreads();
    }
    float r = red[0];
    __syncthreads();
    return r;
}

// ---------------- prep: fp32 -> bf16 flat convert (embed) ----------------
__global__ __launch_bounds__(256) void convert_bf16_kernel(const float* __restrict__ src,
                                                           ushort* __restrict__ dst, long n4) {
    long i = (long)blockIdx.x * 256 + threadIdx.x;
    if (i >= n4) return;
    float4 f = ((const float4*)src)[i];
    ushort u[4] = { f2bf(f.x), f2bf(f.y), f2bf(f.z), f2bf(f.w) };
    ((uint2*)dst)[i] = *(uint2*)u;
}

// ---------------- prep: W (K x N fp32) -> dst (N x K bf16) ----------------
__global__ __launch_bounds__(256) void transpose_bf16_kernel(const float* __restrict__ W,
                                                             ushort* __restrict__ dst,
                                                             int N, int K) {
    __shared__ float tile[32][33];
    int n0 = blockIdx.x * 32, k0 = blockIdx.y * 32;
    int tx = threadIdx.x & 31, ty = threadIdx.x >> 5;
    for (int i = ty; i < 32; i += 8) tile[i][tx] = W[(long)(k0 + i) * N + n0 + tx];
    __syncthreads();
    for (int i = ty; i < 32; i += 8)
        dst[(long)(n0 + i) * K + k0 + tx] = f2bf(tile[tx][i]);
}

// ---------------- embedding gather ----------------
__global__ __launch_bounds__(256) void gather_kernel(const float* __restrict__ embed,
                                                     const int* __restrict__ idx,
                                                     float* __restrict__ x) {
    int t = blockIdx.x;
    long r = idx[t];
    const float4* src = (const float4*)(embed + r * EE);
    float4* dst = (float4*)(x + (long)t * EE);
    for (int i = threadIdx.x; i < EE / 4; i += 256) dst[i] = src[i];
}

// ---------------- layernorm (one block per row) -> bf16 out ----------------
__global__ __launch_bounds__(256) void ln_kernel(const float* __restrict__ x,
                                                 const float* __restrict__ g,
                                                 const float* __restrict__ b,
                                                 ushort* __restrict__ out) {
    __shared__ float red[256];
    int t = blockIdx.x;
    const float* xr = x + (long)t * EE;
    float s = 0.f;
    for (int i = threadIdx.x; i < EE; i += 256) s += xr[i];
    float mu = block_reduce_sum(s, red) * (1.f / EE);
    float vs = 0.f;
    for (int i = threadIdx.x; i < EE; i += 256) { float d = xr[i] - mu; vs += d * d; }
    float var = block_reduce_sum(vs, red) * (1.f / EE);
    float rstd = rsqrtf(var + LEPS);
    ushort* orow = out + (long)t * EE;
    for (int i = threadIdx.x; i < EE; i += 256)
        orow[i] = f2bf((xr[i] - mu) * rstd * g[i] + b[i]);
}

// ------- fused split-K reduce + residual add + LayerNorm -------------------
// x[t] += sum_k part[k][t]; out = LN(x[t]) in bf16.  One block per row,
// each thread owns one float4 (EE=1024 = 256*4) -> no re-reads.
__global__ __launch_bounds__(256) void reduce_ln_kernel(const float* __restrict__ part,
                                                        float* __restrict__ x,
                                                        const float* __restrict__ g,
                                                        const float* __restrict__ b,
                                                        ushort* __restrict__ out, int SK) {
    __shared__ float red[256];
    int t = blockIdx.x;
    int tid = threadIdx.x;
    float4 v = ((const float4*)(x + (long)t * EE))[tid];
    for (int k = 0; k < SK; ++k) {
        float4 pp = ((const float4*)(part + (long)k * TT * EE + (long)t * EE))[tid];
        v.x += pp.x; v.y += pp.y; v.z += pp.z; v.w += pp.w;
    }
    ((float4*)(x + (long)t * EE))[tid] = v;
    float s = v.x + v.y + v.z + v.w;
    float mu = block_reduce_sum(s, red) * (1.f / EE);
    float d0 = v.x - mu, d1 = v.y - mu, d2 = v.z - mu, d3 = v.w - mu;
    float vs = d0 * d0 + d1 * d1 + d2 * d2 + d3 * d3;
    float var = block_reduce_sum(vs, red) * (1.f / EE);
    float rstd = rsqrtf(var + LEPS);
    float4 gg = ((const float4*)g)[tid];
    float4 bb = ((const float4*)b)[tid];
    ushort4 o;
    o.x = f2bf(d0 * rstd * gg.x + bb.x);
    o.y = f2bf(d1 * rstd * gg.y + bb.y);
    o.z = f2bf(d2 * rstd * gg.z + bb.z);
    o.w = f2bf(d3 * rstd * gg.w + bb.w);
    ((ushort4*)(out + (long)t * EE))[tid] = o;
}

// ---------------- bf16 MFMA GEMM: C[M,N] = A[M,K] @ Bt[N,K]^T ----------------
// Grid: x = (M/128)*(N/128) linear, XCD-chunked bijective swizzle, row-fastest
// tile order; y = split-K slices (M_PART only).
#define M_QKV    0   // bf16 out + fused RoPE on Q/K head dims [0,32)
#define M_FF1    1   // bf16 out + GELU
#define M_PART   2   // fp32 partial at Cv + blockIdx.y*M*N  (split-K)
#define M_LMHEAD 3   // fp32 out + per-row (max, sumexp) partials into lstats

template<int MODE>
__global__ __launch_bounds__(256) void gemm_bf16(const ushort* __restrict__ A,
                                                 const ushort* __restrict__ B,
                                                 void* __restrict__ Cv,
                                                 float* __restrict__ lstats,
                                                 int M, int N, int K) {
    __shared__ char lds[16384];   // A tile 8KB @0, B tile 8KB @8192
    const int tid = threadIdx.x;
    const int lane = tid & 63;
    const int w = tid >> 6;

    // --- XCD-chunked bijective swizzle (m204), row-fastest tile order ---
    const int nwg = gridDim.x;
    const int lin = blockIdx.x;
    const int q8 = nwg >> 3, r8 = nwg & 7;
    const int xcd = lin & 7, loc = lin >> 3;
    const int wg = (xcd < r8 ? xcd * (q8 + 1) : r8 * (q8 + 1) + (xcd - r8) * q8) + loc;
    const int MB = M >> 7;
    const int row0 = (wg % MB) * 128;
    const int col0 = (wg / MB) * 128;

    // --- split-K slice ---
    const int nsl = gridDim.y;
    const int kslice = K / nsl;
    const long koff = (long)blockIdx.y * kslice;

    const char* ga[2]; const char* gb[2];
    char* la[2]; char* lb[2];
    #pragma unroll
    for (int r = 0; r < 2; ++r) {
        int c = r * 256 + tid;
        ga[r] = (const char*)A + ((long)(row0 + (c >> 2)) * K + koff) * 2 + (c & 3) * 16;
        gb[r] = (const char*)B + ((long)(col0 + (c >> 2)) * K + koff) * 2 + (c & 3) * 16;
        int wc = r * 256 + w * 64;
        la[r] = lds + wc * 16;
        lb[r] = lds + 8192 + wc * 16;
    }

    floatx4 acc[4][4];
    #pragma unroll
    for (int i = 0; i < 4; ++i)
        #pragma unroll
        for (int j = 0; j < 4; ++j) acc[i][j] = {0.f, 0.f, 0.f, 0.f};

    const int mbase = (w >> 1) * 64;
    const int nbase = (w & 1) * 64;
    const int lr = lane & 15;
    const int ko = (lane >> 4) * 16;

    for (int k0 = 0; k0 < kslice; k0 += 32) {
        #pragma unroll
        for (int r = 0; r < 2; ++r) {
            __builtin_amdgcn_global_load_lds(
                (const __attribute__((address_space(1))) void*)ga[r],
                (__attribute__((address_space(3))) void*)la[r], 16, 0, 0);
            __builtin_amdgcn_global_load_lds(
                (const __attribute__((address_space(1))) void*)gb[r],
                (__attribute__((address_space(3))) void*)lb[r], 16, 0, 0);
            ga[r] += 64; gb[r] += 64;
        }
        __syncthreads();
        short8 af[4], bfr[4];
        #pragma unroll
        for (int i = 0; i < 4; ++i)
            af[i] = *(const short8*)(lds + (mbase + i * 16 + lr) * 64 + ko);
        #pragma unroll
        for (int j = 0; j < 4; ++j)
            bfr[j] = *(const short8*)(lds + 8192 + (nbase + j * 16 + lr) * 64 + ko);
        #pragma unroll
        for (int i = 0; i < 4; ++i)
            #pragma unroll
            for (int j = 0; j < 4; ++j)
                acc[i][j] = __builtin_amdgcn_mfma_f32_16x16x32_bf16(af[i], bfr[j], acc[i][j], 0, 0, 0);
        __syncthreads();
    }

    const int orow = (lane >> 4) * 4;
    const int ocol = lane & 15;

    // Fused RoPE: head dims d=ocol (j=0) pair with d+16 (j=1); Q+K cols < 1280.
    if (MODE == M_QKV && (col0 + nbase) < (EE + NKVH * DHEAD)) {
        float th = expf(-(float)ocol * 0.5756462732485114f);  // ln(10000)/16
        #pragma unroll
        for (int i = 0; i < 4; ++i)
            #pragma unroll
            for (int r = 0; r < 4; ++r) {
                float ang = (float)(row0 + mbase + i * 16 + orow + r) * th;
                float c = cosf(ang), s = sinf(ang);
                float a = acc[i][0][r], bb = acc[i][1][r];
                acc[i][0][r] = a * c - bb * s;
                acc[i][1][r] = bb * c + a * s;
            }
    }

    #pragma unroll
    for (int i = 0; i < 4; ++i) {
        #pragma unroll
        for (int j = 0; j < 4; ++j) {
            #pragma unroll
            for (int r = 0; r < 4; ++r) {
                long off = (long)(row0 + mbase + i * 16 + orow + r) * N
                         + (col0 + nbase + j * 16 + ocol);
                float v = acc[i][j][r];
                if (MODE == M_FF1) v = 0.5f * v * (1.f + erff(v * 0.70710678118654752f));
                if (MODE == M_QKV || MODE == M_FF1) {
                    ((ushort*)Cv)[off] = f2bf(v);
                } else {
                    ((float*)Cv + (long)blockIdx.y * (long)M * N)[off] = v;
                }
            }
        }
    }

    // Per-row logsumexp partials over this block's 128 cols -> lstats[row][colblk]
    if (MODE == M_LMHEAD) {
        float rm[4][4], rs[4][4];
        #pragma unroll
        for (int i = 0; i < 4; ++i)
            #pragma unroll
            for (int r = 0; r < 4; ++r) {
                float m0 = fmaxf(fmaxf(acc[i][0][r], acc[i][1][r]),
                                 fmaxf(acc[i][2][r], acc[i][3][r]));
                float s0 = expf(acc[i][0][r] - m0) + expf(acc[i][1][r] - m0)
                         + expf(acc[i][2][r] - m0) + expf(acc[i][3][r] - m0);
                #pragma unroll
                for (int off = 1; off < 16; off <<= 1) {
                    float om = __shfl_xor(m0, off);
                    float os = __shfl_xor(s0, off);
                    float nm = fmaxf(m0, om);
                    s0 = s0 * expf(m0 - nm) + os * expf(om - nm);
                    m0 = nm;
                }
                rm[i][r] = m0; rs[i][r] = s0;
            }
        float2* msb = (float2*)lds;   // [4 waves][64 rows] = 2KB, K-loop done
        if (ocol == 0) {
            #pragma unroll
            for (int i = 0; i < 4; ++i)
                #pragma unroll
                for (int r = 0; r < 4; ++r)
                    msb[w * 64 + i * 16 + orow + r] = make_float2(rm[i][r], rs[i][r]);
        }
        __syncthreads();
        if (tid < 128) {
            int half = tid >> 6, rloc = tid & 63;
            float2 a = msb[(half * 2) * 64 + rloc];
            float2 bq = msb[(half * 2 + 1) * 64 + rloc];
            float nm = fmaxf(a.x, bq.x);
            float ns = a.y * expf(a.x - nm) + bq.y * expf(bq.x - nm);
            ((float2*)lstats)[(long)(row0 + half * 64 + rloc) * (N >> 7) + (col0 >> 7)]
                = make_float2(nm, ns);
        }
    }
}

// ---------------- scores = Q @ K^T per head (causal-skip), fp32 out ---------
__global__ __launch_bounds__(256) void scores_gemm(const ushort* __restrict__ qkv,
                                                   float* __restrict__ scores) {
    __shared__ char lds[16384];
    const int tid = threadIdx.x;
    const int lane = tid & 63;
    const int w = tid >> 6;
    const int col0 = blockIdx.x * 128, row0 = blockIdx.y * 128, h = blockIdx.z;
    if (col0 > row0) return;   // fully-masked causal tile

    const ushort* A = qkv + h * DHEAD;
    const ushort* B = qkv + EE + (h >> 2) * DHEAD;

    const char* ga[2]; const char* gb[2];
    char* la[2]; char* lb[2];
    #pragma unroll
    for (int r = 0; r < 2; ++r) {
        int c = r * 256 + tid;
        ga[r] = (const char*)A + (long)(row0 + (c >> 2)) * QKVN * 2 + (c & 3) * 16;
        gb[r] = (const char*)B + (long)(col0 + (c >> 2)) * QKVN * 2 + (c & 3) * 16;
        int wc = r * 256 + w * 64;
        la[r] = lds + wc * 16;
        lb[r] = lds + 8192 + wc * 16;
    }

    floatx4 acc[4][4];
    #pragma unroll
    for (int i = 0; i < 4; ++i)
        #pragma unroll
        for (int j = 0; j < 4; ++j) acc[i][j] = {0.f, 0.f, 0.f, 0.f};

    const int mbase = (w >> 1) * 64;
    const int nbase = (w & 1) * 64;
    const int lr = lane & 15;
    const int ko = (lane >> 4) * 16;

    for (int k0 = 0; k0 < DHEAD; k0 += 32) {
        #pragma unroll
        for (int r = 0; r < 2; ++r) {
            __builtin_amdgcn_global_load_lds(
                (const __attribute__((address_space(1))) void*)ga[r],
                (__attribute__((address_space(3))) void*)la[r], 16, 0, 0);
            __builtin_amdgcn_global_load_lds(
                (const __attribute__((address_space(1))) void*)gb[r],
                (__attribute__((address_space(3))) void*)lb[r], 16, 0, 0);
            ga[r] += 64; gb[r] += 64;
        }
        __syncthreads();
        short8 af[4], bfr[4];
        #pragma unroll
        for (int i = 0; i < 4; ++i)
            af[i] = *(const short8*)(lds + (mbase + i * 16 + lr) * 64 + ko);
        #pragma unroll
        for (int j = 0; j < 4; ++j)
            bfr[j] = *(const short8*)(lds + 8192 + (nbase + j * 16 + lr) * 64 + ko);
        #pragma unroll
        for (int i = 0; i < 4; ++i)
            #pragma unroll
            for (int j = 0; j < 4; ++j)
                acc[i][j] = __builtin_amdgcn_mfma_f32_16x16x32_bf16(af[i], bfr[j], acc[i][j], 0, 0, 0);
        __syncthreads();
    }

    float* C = scores + (long)h * TT * TT;
    const int orow = (lane >> 4) * 4;
    const int ocol = lane & 15;
    #pragma unroll
    for (int i = 0; i < 4; ++i)
        #pragma unroll
        for (int j = 0; j < 4; ++j)
            #pragma unroll
            for (int r = 0; r < 4; ++r)
                C[(long)(row0 + mbase + i * 16 + orow + r) * TT
                  + (col0 + nbase + j * 16 + ocol)] = acc[i][j][r];
}

// ---------------- softmax + gate; one WAVE per row, no barriers -------------
// block = 4 waves = 4 rows; each lane holds 16 elems (4 float4).
__global__ __launch_bounds__(256) void softmax_gate_kernel(float* __restrict__ scores,
                                                           const float* __restrict__ gate) {
    int h = blockIdx.x;
    int t = blockIdx.y * 4 + (threadIdx.x >> 6);
    int lane = threadIdx.x & 63;
    float* row = scores + (long)h * TT * TT + (long)t * TT;

    float4 v[4];
    float lmax = -INFINITY;
    #pragma unroll
    for (int q = 0; q < 4; ++q) {
        int u = lane + q * 64;
        v[q] = ((const float4*)row)[u];
        int s0 = u * 4;
        v[q].x = (s0 + 0 <= t) ? v[q].x * 0.125f : -INFINITY;
        v[q].y = (s0 + 1 <= t) ? v[q].y * 0.125f : -INFINITY;
        v[q].z = (s0 + 2 <= t) ? v[q].z * 0.125f : -INFINITY;
        v[q].w = (s0 + 3 <= t) ? v[q].w * 0.125f : -INFINITY;
        lmax = fmaxf(lmax, fmaxf(fmaxf(v[q].x, v[q].y), fmaxf(v[q].z, v[q].w)));
    }
    #pragma unroll
    for (int off = 1; off < 64; off <<= 1)
        lmax = fmaxf(lmax, __shfl_xor(lmax, off));

    float e[16];
    float lsum = 0.f;
    #pragma unroll
    for (int q = 0; q < 4; ++q) {
        e[q * 4 + 0] = expf(v[q].x - lmax);
        e[q * 4 + 1] = expf(v[q].y - lmax);
        e[q * 4 + 2] = expf(v[q].z - lmax);
        e[q * 4 + 3] = expf(v[q].w - lmax);
        lsum += e[q * 4 + 0] + e[q * 4 + 1] + e[q * 4 + 2] + e[q * 4 + 3];
    }
    #pragma unroll
    for (int off = 1; off < 64; off <<= 1)
        lsum += __shfl_xor(lsum, off);

    float inv = 1.f / lsum;
    float thr = 1.f / (1.f + expf(-gate[h]));
    ushort* prow = (ushort*)row;   // alias — all wave reads done (shfl-synced)
    #pragma unroll
    for (int q = 0; q < 4; ++q) {
        ushort4 o;
        float p;
        p = e[q * 4 + 0] * inv; o.x = f2bf(p >= thr ? p : 0.f);
        p = e[q * 4 + 1] * inv; o.y = f2bf(p >= thr ? p : 0.f);
        p = e[q * 4 + 2] * inv; o.z = f2bf(p >= thr ? p : 0.f);
        p = e[q * 4 + 3] * inv; o.w = f2bf(p >= thr ? p : 0.f);
        ((ushort4*)prow)[lane + q * 64] = o;
    }
}

// ---------------- V^T: qkv v-part [TT,256] -> VT [256,TT] bf16 --------------
__global__ __launch_bounds__(256) void vtrans_kernel(const ushort* __restrict__ qkv,
                                                     ushort* __restrict__ VT) {
    __shared__ ushort tile[32][33];
    int s0 = blockIdx.x * 32, d0 = blockIdx.y * 32;
    int tx = threadIdx.x & 31, ty = threadIdx.x >> 5;
    for (int i = ty; i < 32; i += 8)
        tile[i][tx] = qkv[(long)(s0 + i) * QKVN + (EE + NKVH * DHEAD) + d0 + tx];
    __syncthreads();
    for (int i = ty; i < 32; i += 8)
        VT[(long)(d0 + i) * TT + s0 + tx] = tile[tx][i];
}

// ---------------- y = P @ V per head: tile 128x64, causal kmax --------------
__global__ __launch_bounds__(256) void pv_gemm(const float* __restrict__ scores,
                                               const ushort* __restrict__ VT,
                                               ushort* __restrict__ y) {
    __shared__ char lds[12288];   // A 8KB @0, B 4KB @8192
    const int tid = threadIdx.x;
    const int lane = tid & 63;
    const int w = tid >> 6;
    const int row0 = blockIdx.x * 128, h = blockIdx.y;

    const char* Pb = (const char*)(scores + (long)h * TT * TT);  // P rows: 4096B stride
    const char* Bv = (const char*)(VT + (long)(h >> 2) * DHEAD * TT);

    const char* ga[2]; char* la[2];
    #pragma unroll
    for (int r = 0; r < 2; ++r) {
        int c = r * 256 + tid;
        ga[r] = Pb + (long)(row0 + (c >> 2)) * 4096 + (c & 3) * 16;
        la[r] = lds + (r * 256 + w * 64) * 16;
    }
    const char* gb = Bv + (long)(tid >> 2) * 2048 + (tid & 3) * 16;
    char* lb = lds + 8192 + (w * 64) * 16;

    floatx4 acc[2][4];
    #pragma unroll
    for (int i = 0; i < 2; ++i)
        #pragma unroll
        for (int j = 0; j < 4; ++j) acc[i][j] = {0.f, 0.f, 0.f, 0.f};

    const int mbase = w * 32;
    const int lr = lane & 15;
    const int ko = (lane >> 4) * 16;

    const int kmax = row0 + 128;   // P[t][s]=0 for s>t, tile max t = row0+127
    for (int k0 = 0; k0 < kmax; k0 += 32) {
        #pragma unroll
        for (int r = 0; r < 2; ++r) {
            __builtin_amdgcn_global_load_lds(
                (const __attribute__((address_space(1))) void*)ga[r],
                (__attribute__((address_space(3))) void*)la[r], 16, 0, 0);
            ga[r] += 64;
        }
        __builtin_amdgcn_global_load_lds(
            (const __attribute__((address_space(1))) void*)gb,
            (__attribute__((address_space(3))) void*)lb, 16, 0, 0);
        gb += 64;
        __syncthreads();
        short8 af[2], bfr[4];
        #pragma unroll
        for (int i = 0; i < 2; ++i)
            af[i] = *(const short8*)(lds + (mbase + i * 16 + lr) * 64 + ko);
        #pragma unroll
        for (int j = 0; j < 4; ++j)
            bfr[j] = *(const short8*)(lds + 8192 + (j * 16 + lr) * 64 + ko);
        #pragma unroll
        for (int i = 0; i < 2; ++i)
            #pragma unroll
            for (int j = 0; j < 4; ++j)
                acc[i][j] = __builtin_amdgcn_mfma_f32_16x16x32_bf16(af[i], bfr[j], acc[i][j], 0, 0, 0);
        __syncthreads();
    }

    const int orow = (lane >> 4) * 4;
    const int ocol = lane & 15;
    #pragma unroll
    for (int i = 0; i < 2; ++i)
        #pragma unroll
        for (int j = 0; j < 4; ++j)
            #pragma unroll
            for (int r = 0; r < 4; ++r)
                y[(long)(row0 + mbase + i * 16 + orow + r) * EE
                  + h * DHEAD + j * 16 + ocol] = f2bf(acc[i][j][r]);
}

// ---------------- loss: combine per-colblock (max,sumexp) partials ----------
__global__ __launch_bounds__(64) void row_loss_kernel(const float* __restrict__ logits,
                                                      const float* __restrict__ lstats,
                                                      const int* __restrict__ targets,
                                                      float* __restrict__ row_loss) {
    int t = blockIdx.x;
    int lane = threadIdx.x;
    const float2* st = (const float2*)lstats + (long)t * (VV / 128);
    float m = -INFINITY, s = 0.f;
    for (int i = lane; i < VV / 128; i += 64) {
        float2 v = st[i];
        float nm = fmaxf(m, v.x);
        s = s * expf(m - nm) + v.y * expf(v.x - nm);
        m = nm;
    }
    #pragma unroll
    for (int off = 1; off < 64; off <<= 1) {
        float om = __shfl_xor(m, off);
        float os = __shfl_xor(s, off);
        float nm = fmaxf(m, om);
        s = s * expf(m - nm) + os * expf(om - nm);
        m = nm;
    }
    if (lane == 0)
        row_loss[t] = logf(s) + m - logits[(long)t * VV + targets[t]];
}

__global__ __launch_bounds__(256) void final_loss_kernel(const float* __restrict__ row_loss,
                                                         float* __restrict__ out) {
    __shared__ float red[256];
    float s = 0.f;
    for (int i = threadIdx.x; i < TT; i += 256) s += row_loss[i];
    float tot = block_reduce_sum(s, red);
    if (threadIdx.x == 0) out[0] = tot * (1.f / TT);
}

// ---------------- host orchestration ----------------
extern "C" void kernel_launch(void* const* d_in, const int* in_sizes, int n_in,
                              void* d_out, int out_size, void* d_ws, size_t ws_size,
                              hipStream_t stream) {
    const float* embed = (const float*)d_in[0];
    const float* ln1_g = (const float*)d_in[1];
    const float* ln1_b = (const float*)d_in[2];
    const float* Wq    = (const float*)d_in[3];
    const float* Wk    = (const float*)d_in[4];
    const float* Wv    = (const float*)d_in[5];
    const float* Wo    = (const float*)d_in[6];
    const float* gate  = (const float*)d_in[7];
    const float* ln2_g = (const float*)d_in[8];
    const float* ln2_b = (const float*)d_in[9];
    const float* W1    = (const float*)d_in[10];
    const float* W2    = (const float*)d_in[11];
    const float* lnf_g = (const float*)d_in[12];
    const float* lnf_b = (const float*)d_in[13];
    const int*   idx   = (const int*)d_in[14];
    const int*   tgt   = (const int*)d_in[15];
    float* out = (float*)d_out;

    char* p = (char*)d_ws;
    float*  x      = (float*)p;  p += (long)TT * EE * 4;
    ushort* xn     = (ushort*)p; p += (long)TT * EE * 2;
    ushort* qkvb   = (ushort*)p; p += (long)TT * QKVN * 2;
    ushort* y      = (ushort*)p; p += (long)TT * EE * 2;
    ushort* h1     = (ushort*)p; p += (long)TT * FF * 2;
    float*  rls    = (float*)p;  p += (long)TT * 4;
    ushort* VT     = (ushort*)p; p += (long)NKVH * DHEAD * TT * 2;
    float*  scores = (float*)p;  p += (long)NH * TT * TT * 4;
    ushort* wqkvT  = (ushort*)p; p += (long)2 * QKVN * EE * 2;
    ushort* woT    = (ushort*)p; p += (long)2 * EE * EE * 2;
    ushort* w1T    = (ushort*)p; p += (long)2 * FF * EE * 2;
    ushort* w2T    = (ushort*)p; p += (long)2 * EE * FF * 2;
    ushort* embB   = (ushort*)p; p += (long)VV * EE * 2;

    // split-K partial / lstats scratch: alias scores (dead at those points)
    float* gpart = scores;

    // ---- prep: bf16 conversions / transposes ----
    convert_bf16_kernel<<<((long)VV * EE / 4 + 255) / 256, 256, 0, stream>>>(embed, embB, (long)VV * EE / 4);
    for (int l = 0; l < 2; ++l) {
        transpose_bf16_kernel<<<dim3(EE / 32, EE / 32), 256, 0, stream>>>(
            Wq + (long)l * EE * EE, wqkvT + (long)l * QKVN * EE, EE, EE);
        transpose_bf16_kernel<<<dim3(NKVH * DHEAD / 32, EE / 32), 256, 0, stream>>>(
            Wk + (long)l * EE * NKVH * DHEAD, wqkvT + (long)l * QKVN * EE + (long)EE * EE, NKVH * DHEAD, EE);
        transpose_bf16_kernel<<<dim3(NKVH * DHEAD / 32, EE / 32), 256, 0, stream>>>(
            Wv + (long)l * EE * NKVH * DHEAD, wqkvT + (long)l * QKVN * EE + (long)(EE + NKVH * DHEAD) * EE, NKVH * DHEAD, EE);
        transpose_bf16_kernel<<<dim3(EE / 32, EE / 32), 256, 0, stream>>>(
            Wo + (long)l * EE * EE, woT + (long)l * EE * EE, EE, EE);
        transpose_bf16_kernel<<<dim3(FF / 32, EE / 32), 256, 0, stream>>>(
            W1 + (long)l * EE * FF, w1T + (long)l * FF * EE, FF, EE);
        transpose_bf16_kernel<<<dim3(EE / 32, FF / 32), 256, 0, stream>>>(
            W2 + (long)l * FF * EE, w2T + (long)l * EE * FF, EE, FF);
    }

    gather_kernel<<<TT, 256, 0, stream>>>(embed, idx, x);
    ln_kernel<<<TT, 256, 0, stream>>>(x, ln1_g, ln1_b, xn);   // first ln1 (layer 0)

    for (int r = 0; r < 2; ++r) {
        for (int l = 0; l < 2; ++l) {
            // QKV projection with fused RoPE
            gemm_bf16<M_QKV><<<dim3((TT / 128) * (QKVN / 128)), 256, 0, stream>>>(
                xn, wqkvT + (long)l * QKVN * EE, qkvb, nullptr, TT, QKVN, EE);
            vtrans_kernel<<<dim3(TT / 32, NKVH * DHEAD / 32), 256, 0, stream>>>(qkvb, VT);
            scores_gemm<<<dim3(TT / 128, TT / 128, NH), 256, 0, stream>>>(qkvb, scores);
            softmax_gate_kernel<<<dim3(NH, TT / 4), 256, 0, stream>>>(scores, gate + l * NH);
            pv_gemm<<<dim3(TT / 128, NH), 256, 0, stream>>>(scores, VT, y);

            // Wo: split-K=2 partials -> fused reduce + residual + LN2
            gemm_bf16<M_PART><<<dim3((TT / 128) * (EE / 128), 2), 256, 0, stream>>>(
                y, woT + (long)l * EE * EE, gpart, nullptr, TT, EE, EE);
            reduce_ln_kernel<<<TT, 256, 0, stream>>>(
                gpart, x, ln2_g + l * EE, ln2_b + l * EE, xn, 2);

            // FF1 with fused GELU
            gemm_bf16<M_FF1><<<dim3((TT / 128) * (FF / 128)), 256, 0, stream>>>(
                xn, w1T + (long)l * FF * EE, h1, nullptr, TT, FF, EE);

            // FF2: split-K=4 partials -> fused reduce + residual + next LN
            gemm_bf16<M_PART><<<dim3((TT / 128) * (EE / 128), 4), 256, 0, stream>>>(
                h1, w2T + (long)l * EE * FF, gpart, nullptr, TT, EE, FF);
            const float* gn; const float* bn;
            if (r == 1 && l == 1) { gn = lnf_g; bn = lnf_b; }
            else { int lnx = (l == 0) ? 1 : 0; gn = ln1_g + lnx * EE; bn = ln1_b + lnx * EE; }
            reduce_ln_kernel<<<TT, 256, 0, stream>>>(gpart, x, gn, bn, xn, 4);
        }
    }

    // LM head (xn already holds lnf output); lstats partials into gpart
    gemm_bf16<M_LMHEAD><<<dim3((TT / 128) * (VV / 128)), 256, 0, stream>>>(
        xn, embB, out, gpart, TT, VV, EE);

    row_loss_kernel<<<TT, 64, 0, stream>>>(out, gpart, tgt, rls);
    final_loss_kernel<<<1, 256, 0, stream>>>(rls, out + (long)TT * VV);
}

// Round 4
// 1148.994 us; speedup vs baseline: 1.3992x; 1.0325x over previous
//
#include <hip/hip_runtime.h>
#include <math.h>

#define TT 1024
#define VV 32000
#define EE 1024
#define NH 16
#define NKVH 4
#define DHEAD 64
#define QKVN 1536    // E + 2*NKVH*DHEAD
#define FF 4096
#define LEPS 1e-5f

typedef __attribute__((ext_vector_type(8))) short short8;
typedef __attribute__((ext_vector_type(4))) float floatx4;

__device__ __forceinline__ ushort f2bf(float f) {
    unsigned x = __float_as_uint(f);
    unsigned r = (x + 0x7fffu + ((x >> 16) & 1u)) >> 16;
    return (ushort)r;
}
__device__ __forceinline__ float bf2f(ushort u) {
    return __uint_as_float(((unsigned)u) << 16);
}

// ---------------- block reduction helpers (blockDim.x == 256) ----------------
__device__ __forceinline__ float block_reduce_sum(float v, float* red) {
    int tid = threadIdx.x;
    red[tid] = v; __syncthreads();
    for (int off = 128; off > 0; off >>= 1) {
        if (tid < off) red[tid] += red[tid + off];
        __syncthreads();
    }
    float r = red[0];
    __syncthreads();
    return r;
}
__device__ __forceinline__ float block_reduce_max(float v, float* red) {
    int tid = threadIdx.x;
    red[tid] = v; __syncthreads();
    for (int off = 128; off > 0; off >>= 1) {
        if (tid < off) red[tid] = fmaxf(red[tid], red[tid + off]);
        __syncthreads();
    }
    float r = red[0];
    __syncthreads();
    return r;
}

// ---------------- prep: fp32 -> bf16 flat convert (embed) ----------------
__global__ __launch_bounds__(256) void convert_bf16_kernel(const float* __restrict__ src,
                                                           ushort* __restrict__ dst, long n4) {
    long i = (long)blockIdx.x * 256 + threadIdx.x;
    if (i >= n4) return;
    float4 f = ((const float4*)src)[i];
    ushort u[4] = { f2bf(f.x), f2bf(f.y), f2bf(f.z), f2bf(f.w) };
    ((uint2*)dst)[i] = *(uint2*)u;
}

// ---------------- prep: W (K x N fp32) -> dst (N x K bf16) ----------------
__global__ __launch_bounds__(256) void transpose_bf16_kernel(const float* __restrict__ W,
                                                             ushort* __restrict__ dst,
                                                             int N, int K) {
    __shared__ float tile[32][33];
    int n0 = blockIdx.x * 32, k0 = blockIdx.y * 32;
    int tx = threadIdx.x & 31, ty = threadIdx.x >> 5;
    for (int i = ty; i < 32; i += 8) tile[i][tx] = W[(long)(k0 + i) * N + n0 + tx];
    __syncthreads();
    for (int i = ty; i < 32; i += 8)
        dst[(long)(n0 + i) * K + k0 + tx] = f2bf(tile[tx][i]);
}

// ---------------- embedding gather ----------------
__global__ __launch_bounds__(256) void gather_kernel(const float* __restrict__ embed,
                                                     const int* __restrict__ idx,
                                                     float* __restrict__ x) {
    int t = blockIdx.x;
    long r = idx[t];
    const float4* src = (const float4*)(embed + r * EE);
    float4* dst = (float4*)(x + (long)t * EE);
    for (int i = threadIdx.x; i < EE / 4; i += 256) dst[i] = src[i];
}

// ---------------- layernorm (one block per row) -> bf16 out ----------------
__global__ __launch_bounds__(256) void ln_kernel(const float* __restrict__ x,
                                                 const float* __restrict__ g,
                                                 const float* __restrict__ b,
                                                 ushort* __restrict__ out) {
    __shared__ float red[256];
    int t = blockIdx.x;
    const float* xr = x + (long)t * EE;
    float s = 0.f;
    for (int i = threadIdx.x; i < EE; i += 256) s += xr[i];
    float mu = block_reduce_sum(s, red) * (1.f / EE);
    float vs = 0.f;
    for (int i = threadIdx.x; i < EE; i += 256) { float d = xr[i] - mu; vs += d * d; }
    float var = block_reduce_sum(vs, red) * (1.f / EE);
    float rstd = rsqrtf(var + LEPS);
    ushort* orow = out + (long)t * EE;
    for (int i = threadIdx.x; i < EE; i += 256)
        orow[i] = f2bf((xr[i] - mu) * rstd * g[i] + b[i]);
}

// ------- fused split-K reduce + residual add + LayerNorm -------------------
__global__ __launch_bounds__(256) void reduce_ln_kernel(const float* __restrict__ part,
                                                        float* __restrict__ x,
                                                        const float* __restrict__ g,
                                                        const float* __restrict__ b,
                                                        ushort* __restrict__ out, int SK) {
    __shared__ float red[256];
    int t = blockIdx.x;
    int tid = threadIdx.x;
    float4 v = ((const float4*)(x + (long)t * EE))[tid];
    for (int k = 0; k < SK; ++k) {
        float4 pp = ((const float4*)(part + (long)k * TT * EE + (long)t * EE))[tid];
        v.x += pp.x; v.y += pp.y; v.z += pp.z; v.w += pp.w;
    }
    ((float4*)(x + (long)t * EE))[tid] = v;
    float s = v.x + v.y + v.z + v.w;
    float mu = block_reduce_sum(s, red) * (1.f / EE);
    float d0 = v.x - mu, d1 = v.y - mu, d2 = v.z - mu, d3 = v.w - mu;
    float vs = d0 * d0 + d1 * d1 + d2 * d2 + d3 * d3;
    float var = block_reduce_sum(vs, red) * (1.f / EE);
    float rstd = rsqrtf(var + LEPS);
    float4 gg = ((const float4*)g)[tid];
    float4 bb = ((const float4*)b)[tid];
    ushort4 o;
    o.x = f2bf(d0 * rstd * gg.x + bb.x);
    o.y = f2bf(d1 * rstd * gg.y + bb.y);
    o.z = f2bf(d2 * rstd * gg.z + bb.z);
    o.w = f2bf(d3 * rstd * gg.w + bb.w);
    ((ushort4*)(out + (long)t * EE))[tid] = o;
}

// ---------------- bf16 MFMA GEMM: C[M,N] = A[M,K] @ Bt[N,K]^T ----------------
#define M_QKV    0   // bf16 out + fused RoPE on Q/K head dims [0,32)
#define M_FF1    1   // bf16 out + GELU
#define M_PART   2   // fp32 partial at Cv + blockIdx.y*M*N  (split-K)

template<int MODE>
__global__ __launch_bounds__(256) void gemm_bf16(const ushort* __restrict__ A,
                                                 const ushort* __restrict__ B,
                                                 void* __restrict__ Cv,
                                                 int M, int N, int K) {
    __shared__ char lds[16384];   // A tile 8KB @0, B tile 8KB @8192
    const int tid = threadIdx.x;
    const int lane = tid & 63;
    const int w = tid >> 6;

    // --- XCD-chunked bijective swizzle (m204), row-fastest tile order ---
    const int nwg = gridDim.x;
    const int lin = blockIdx.x;
    const int q8 = nwg >> 3, r8 = nwg & 7;
    const int xcd = lin & 7, loc = lin >> 3;
    const int wg = (xcd < r8 ? xcd * (q8 + 1) : r8 * (q8 + 1) + (xcd - r8) * q8) + loc;
    const int MB = M >> 7;
    const int row0 = (wg % MB) * 128;
    const int col0 = (wg / MB) * 128;

    // --- split-K slice ---
    const int nsl = gridDim.y;
    const int kslice = K / nsl;
    const long koff = (long)blockIdx.y * kslice;

    const char* ga[2]; const char* gb[2];
    char* la[2]; char* lb[2];
    #pragma unroll
    for (int r = 0; r < 2; ++r) {
        int c = r * 256 + tid;
        ga[r] = (const char*)A + ((long)(row0 + (c >> 2)) * K + koff) * 2 + (c & 3) * 16;
        gb[r] = (const char*)B + ((long)(col0 + (c >> 2)) * K + koff) * 2 + (c & 3) * 16;
        int wc = r * 256 + w * 64;
        la[r] = lds + wc * 16;
        lb[r] = lds + 8192 + wc * 16;
    }

    floatx4 acc[4][4];
    #pragma unroll
    for (int i = 0; i < 4; ++i)
        #pragma unroll
        for (int j = 0; j < 4; ++j) acc[i][j] = {0.f, 0.f, 0.f, 0.f};

    const int mbase = (w >> 1) * 64;
    const int nbase = (w & 1) * 64;
    const int lr = lane & 15;
    const int ko = (lane >> 4) * 16;

    for (int k0 = 0; k0 < kslice; k0 += 32) {
        #pragma unroll
        for (int r = 0; r < 2; ++r) {
            __builtin_amdgcn_global_load_lds(
                (const __attribute__((address_space(1))) void*)ga[r],
                (__attribute__((address_space(3))) void*)la[r], 16, 0, 0);
            __builtin_amdgcn_global_load_lds(
                (const __attribute__((address_space(1))) void*)gb[r],
                (__attribute__((address_space(3))) void*)lb[r], 16, 0, 0);
            ga[r] += 64; gb[r] += 64;
        }
        __syncthreads();
        short8 af[4], bfr[4];
        #pragma unroll
        for (int i = 0; i < 4; ++i)
            af[i] = *(const short8*)(lds + (mbase + i * 16 + lr) * 64 + ko);
        #pragma unroll
        for (int j = 0; j < 4; ++j)
            bfr[j] = *(const short8*)(lds + 8192 + (nbase + j * 16 + lr) * 64 + ko);
        #pragma unroll
        for (int i = 0; i < 4; ++i)
            #pragma unroll
            for (int j = 0; j < 4; ++j)
                acc[i][j] = __builtin_amdgcn_mfma_f32_16x16x32_bf16(af[i], bfr[j], acc[i][j], 0, 0, 0);
        __syncthreads();
    }

    const int orow = (lane >> 4) * 4;
    const int ocol = lane & 15;

    // Fused RoPE: head dims d=ocol (j=0) pair with d+16 (j=1); Q+K cols < 1280.
    if (MODE == M_QKV && (col0 + nbase) < (EE + NKVH * DHEAD)) {
        float th = expf(-(float)ocol * 0.5756462732485114f);  // ln(10000)/16
        #pragma unroll
        for (int i = 0; i < 4; ++i)
            #pragma unroll
            for (int r = 0; r < 4; ++r) {
                float ang = (float)(row0 + mbase + i * 16 + orow + r) * th;
                float c = cosf(ang), s = sinf(ang);
                float a = acc[i][0][r], bb = acc[i][1][r];
                acc[i][0][r] = a * c - bb * s;
                acc[i][1][r] = bb * c + a * s;
            }
    }

    #pragma unroll
    for (int i = 0; i < 4; ++i) {
        #pragma unroll
        for (int j = 0; j < 4; ++j) {
            #pragma unroll
            for (int r = 0; r < 4; ++r) {
                long off = (long)(row0 + mbase + i * 16 + orow + r) * N
                         + (col0 + nbase + j * 16 + ocol);
                float v = acc[i][j][r];
                if (MODE == M_FF1) v = 0.5f * v * (1.f + erff(v * 0.70710678118654752f));
                if (MODE == M_QKV || MODE == M_FF1) {
                    ((ushort*)Cv)[off] = f2bf(v);
                } else {
                    ((float*)Cv + (long)blockIdx.y * (long)M * N)[off] = v;
                }
            }
        }
    }
}

// ========== LM head: 256x256 tile, BK=64, counted-vmcnt double-buffer =======
// C[1024,32000] = xn[1024,1024] @ embB[32000,1024]^T, fp32 out + lse partials
// per 256-col block into lstats[row][125].
// LDS 128KB: A dbuf @0 (2x32KB), B dbuf @65536 (2x32KB); tile layout
// [256 rows][64 bf16] with T2 slot-swizzle (slot ^= row&7, 16B slots).
__global__ __launch_bounds__(512, 2) void lmhead_gemm256(const ushort* __restrict__ A,
                                                         const ushort* __restrict__ B,
                                                         float* __restrict__ C,
                                                         float* __restrict__ lstats) {
    __shared__ char lds[131072];
    const int tid = threadIdx.x;
    const int lane = tid & 63;
    const int w = tid >> 6;
    const int wr = w >> 2;        // 0..1  (M half)
    const int wc = w & 3;         // 0..3  (N quarter)

    // XCD-chunked bijective swizzle (m204), row-fastest (MB=4 row tiles)
    const int nwg = gridDim.x;                    // 500
    const int lin = blockIdx.x;
    const int q8 = nwg >> 3, r8 = nwg & 7;
    const int xcd = lin & 7, loc = lin >> 3;
    const int wg = (xcd < r8 ? xcd * (q8 + 1) : r8 * (q8 + 1) + (xcd - r8) * q8) + loc;
    const int row0 = (wg & 3) * 256;              // M = 1024 -> 4 tiles
    const int col0 = (wg >> 2) * 256;             // N = 32000 -> 125 tiles

    const int NT = EE / 64;                       // 16 K-tiles

    // ds_read address components (swizzled): byte = base2 + frag*2048 + ks[kk]
    const int aB2 = (wr * 128 + (lane & 15)) * 128;
    const int bB2 = (wc * 64 + (lane & 15)) * 128;
    const int ks0 = ((0 * 4 + (lane >> 4)) ^ (lane & 7)) * 16;
    const int ks1 = ((1 * 4 + (lane >> 4)) ^ (lane & 7)) * 16;

    // staging components (linear LDS dest, inverse-swizzled global source)
    const int sRow = tid >> 3;                    // 0..63 per issue
    const int sSlotX = tid & 7;                   // dest 16B slot

    floatx4 acc[8][4];
    #pragma unroll
    for (int i = 0; i < 8; ++i)
        #pragma unroll
        for (int j = 0; j < 4; ++j) acc[i][j] = {0.f, 0.f, 0.f, 0.f};

    #define STAGE256(kt, bufsel)                                                     \
    do {                                                                             \
        _Pragma("unroll")                                                            \
        for (int i = 0; i < 4; ++i) {                                                \
            int rowD = i * 64 + sRow;                                                \
            int slotSw = sSlotX ^ (rowD & 7);                                        \
            const char* gsrc = (const char*)A + (long)(row0 + rowD) * 2048           \
                             + (kt) * 128 + slotSw * 16;                             \
            char* ldst = lds + (bufsel) * 32768 + i * 8192 + tid * 16;               \
            __builtin_amdgcn_global_load_lds(                                        \
                (const __attribute__((address_space(1))) void*)gsrc,                 \
                (__attribute__((address_space(3))) void*)ldst, 16, 0, 0);            \
        }                                                                            \
        _Pragma("unroll")                                                            \
        for (int i = 0; i < 4; ++i) {                                                \
            int rowD = i * 64 + sRow;                                                \
            int slotSw = sSlotX ^ (rowD & 7);                                        \
            const char* gsrc = (const char*)B + (long)(col0 + rowD) * 2048           \
                             + (kt) * 128 + slotSw * 16;                             \
            char* ldst = lds + 65536 + (bufsel) * 32768 + i * 8192 + tid * 16;       \
            __builtin_amdgcn_global_load_lds(                                        \
                (const __attribute__((address_space(1))) void*)gsrc,                 \
                (__attribute__((address_space(3))) void*)ldst, 16, 0, 0);            \
        }                                                                            \
    } while (0)

    // prologue: tiles 0 and 1 in flight (16 gloads/wave)
    STAGE256(0, 0);
    STAGE256(1, 1);
    asm volatile("s_waitcnt vmcnt(8)" ::: "memory");   // tile 0 complete
    __builtin_amdgcn_s_barrier();
    __builtin_amdgcn_sched_barrier(0);

    for (int kt = 0; kt < NT; ++kt) {
        const char* Ab = lds + (kt & 1) * 32768;
        const char* Bb = lds + 65536 + (kt & 1) * 32768;

        short8 bfr[4][2];
        #pragma unroll
        for (int fn = 0; fn < 4; ++fn) {
            bfr[fn][0] = *(const short8*)(Bb + bB2 + fn * 2048 + ks0);
            bfr[fn][1] = *(const short8*)(Bb + bB2 + fn * 2048 + ks1);
        }
        __builtin_amdgcn_s_setprio(1);
        #pragma unroll
        for (int fm = 0; fm < 8; ++fm) {
            short8 a0 = *(const short8*)(Ab + aB2 + fm * 2048 + ks0);
            short8 a1 = *(const short8*)(Ab + aB2 + fm * 2048 + ks1);
            #pragma unroll
            for (int fn = 0; fn < 4; ++fn) {
                acc[fm][fn] = __builtin_amdgcn_mfma_f32_16x16x32_bf16(a0, bfr[fn][0], acc[fm][fn], 0, 0, 0);
                acc[fm][fn] = __builtin_amdgcn_mfma_f32_16x16x32_bf16(a1, bfr[fn][1], acc[fm][fn], 0, 0, 0);
            }
        }
        __builtin_amdgcn_s_setprio(0);

        if (kt == NT - 1) break;

        asm volatile("s_waitcnt lgkmcnt(0)" ::: "memory");  // all LDS reads done
        __builtin_amdgcn_s_barrier();                        // buf[kt&1] free
        __builtin_amdgcn_sched_barrier(0);
        if (kt + 2 < NT) {
            STAGE256(kt + 2, kt & 1);
            asm volatile("s_waitcnt vmcnt(8)" ::: "memory"); // tile kt+1 done
        } else {
            asm volatile("s_waitcnt vmcnt(0)" ::: "memory"); // tile kt+1 done
        }
        __builtin_amdgcn_s_barrier();                        // publish buf[(kt+1)&1]
        __builtin_amdgcn_sched_barrier(0);
    }
    #undef STAGE256

    // ---- epilogue: lse partials (max-first), then C store ----
    __syncthreads();                              // LDS now reusable
    float2* msb = (float2*)lds;                   // [4 wc][256 rows] = 8KB
    #pragma unroll
    for (int fm = 0; fm < 8; ++fm) {
        #pragma unroll
        for (int r = 0; r < 4; ++r) {
            float m0 = fmaxf(fmaxf(acc[fm][0][r], acc[fm][1][r]),
                             fmaxf(acc[fm][2][r], acc[fm][3][r]));
            #pragma unroll
            for (int off = 1; off < 16; off <<= 1)
                m0 = fmaxf(m0, __shfl_xor(m0, off));
            float s0 = expf(acc[fm][0][r] - m0) + expf(acc[fm][1][r] - m0)
                     + expf(acc[fm][2][r] - m0) + expf(acc[fm][3][r] - m0);
            #pragma unroll
            for (int off = 1; off < 16; off <<= 1)
                s0 += __shfl_xor(s0, off);
            if ((lane & 15) == 0)
                msb[wc * 256 + wr * 128 + fm * 16 + (lane >> 4) * 4 + r] = make_float2(m0, s0);
        }
    }
    __syncthreads();
    if (tid < 256) {
        float2 v = msb[tid];
        float m = v.x, s = v.y;
        #pragma unroll
        for (int q = 1; q < 4; ++q) {
            float2 u = msb[q * 256 + tid];
            float nm = fmaxf(m, u.x);
            s = s * expf(m - nm) + u.y * expf(u.x - nm);
            m = nm;
        }
        ((float2*)lstats)[(long)(row0 + tid) * 125 + (col0 >> 8)] = make_float2(m, s);
    }

    #pragma unroll
    for (int fm = 0; fm < 8; ++fm)
        #pragma unroll
        for (int fn = 0; fn < 4; ++fn)
            #pragma unroll
            for (int r = 0; r < 4; ++r)
                C[(long)(row0 + wr * 128 + fm * 16 + (lane >> 4) * 4 + r) * VV
                  + col0 + wc * 64 + fn * 16 + (lane & 15)] = acc[fm][fn][r];
}

// ---------------- scores = Q @ K^T per head (causal-skip), fp32 out ---------
__global__ __launch_bounds__(256) void scores_gemm(const ushort* __restrict__ qkv,
                                                   float* __restrict__ scores) {
    __shared__ char lds[16384];
    const int tid = threadIdx.x;
    const int lane = tid & 63;
    const int w = tid >> 6;
    const int col0 = blockIdx.x * 128, row0 = blockIdx.y * 128, h = blockIdx.z;
    if (col0 > row0) return;   // fully-masked causal tile

    const ushort* A = qkv + h * DHEAD;
    const ushort* B = qkv + EE + (h >> 2) * DHEAD;

    const char* ga[2]; const char* gb[2];
    char* la[2]; char* lb[2];
    #pragma unroll
    for (int r = 0; r < 2; ++r) {
        int c = r * 256 + tid;
        ga[r] = (const char*)A + (long)(row0 + (c >> 2)) * QKVN * 2 + (c & 3) * 16;
        gb[r] = (const char*)B + (long)(col0 + (c >> 2)) * QKVN * 2 + (c & 3) * 16;
        int wc = r * 256 + w * 64;
        la[r] = lds + wc * 16;
        lb[r] = lds + 8192 + wc * 16;
    }

    floatx4 acc[4][4];
    #pragma unroll
    for (int i = 0; i < 4; ++i)
        #pragma unroll
        for (int j = 0; j < 4; ++j) acc[i][j] = {0.f, 0.f, 0.f, 0.f};

    const int mbase = (w >> 1) * 64;
    const int nbase = (w & 1) * 64;
    const int lr = lane & 15;
    const int ko = (lane >> 4) * 16;

    for (int k0 = 0; k0 < DHEAD; k0 += 32) {
        #pragma unroll
        for (int r = 0; r < 2; ++r) {
            __builtin_amdgcn_global_load_lds(
                (const __attribute__((address_space(1))) void*)ga[r],
                (__attribute__((address_space(3))) void*)la[r], 16, 0, 0);
            __builtin_amdgcn_global_load_lds(
                (const __attribute__((address_space(1))) void*)gb[r],
                (__attribute__((address_space(3))) void*)lb[r], 16, 0, 0);
            ga[r] += 64; gb[r] += 64;
        }
        __syncthreads();
        short8 af[4], bfr[4];
        #pragma unroll
        for (int i = 0; i < 4; ++i)
            af[i] = *(const short8*)(lds + (mbase + i * 16 + lr) * 64 + ko);
        #pragma unroll
        for (int j = 0; j < 4; ++j)
            bfr[j] = *(const short8*)(lds + 8192 + (nbase + j * 16 + lr) * 64 + ko);
        #pragma unroll
        for (int i = 0; i < 4; ++i)
            #pragma unroll
            for (int j = 0; j < 4; ++j)
                acc[i][j] = __builtin_amdgcn_mfma_f32_16x16x32_bf16(af[i], bfr[j], acc[i][j], 0, 0, 0);
        __syncthreads();
    }

    float* C = scores + (long)h * TT * TT;
    const int orow = (lane >> 4) * 4;
    const int ocol = lane & 15;
    #pragma unroll
    for (int i = 0; i < 4; ++i)
        #pragma unroll
        for (int j = 0; j < 4; ++j)
            #pragma unroll
            for (int r = 0; r < 4; ++r)
                C[(long)(row0 + mbase + i * 16 + orow + r) * TT
                  + (col0 + nbase + j * 16 + ocol)] = acc[i][j][r];
}

// ---------------- softmax + gate; one WAVE per row, no barriers -------------
__global__ __launch_bounds__(256) void softmax_gate_kernel(float* __restrict__ scores,
                                                           const float* __restrict__ gate) {
    int h = blockIdx.x;
    int t = blockIdx.y * 4 + (threadIdx.x >> 6);
    int lane = threadIdx.x & 63;
    float* row = scores + (long)h * TT * TT + (long)t * TT;

    float4 v[4];
    float lmax = -INFINITY;
    #pragma unroll
    for (int q = 0; q < 4; ++q) {
        int u = lane + q * 64;
        v[q] = ((const float4*)row)[u];
        int s0 = u * 4;
        v[q].x = (s0 + 0 <= t) ? v[q].x * 0.125f : -INFINITY;
        v[q].y = (s0 + 1 <= t) ? v[q].y * 0.125f : -INFINITY;
        v[q].z = (s0 + 2 <= t) ? v[q].z * 0.125f : -INFINITY;
        v[q].w = (s0 + 3 <= t) ? v[q].w * 0.125f : -INFINITY;
        lmax = fmaxf(lmax, fmaxf(fmaxf(v[q].x, v[q].y), fmaxf(v[q].z, v[q].w)));
    }
    #pragma unroll
    for (int off = 1; off < 64; off <<= 1)
        lmax = fmaxf(lmax, __shfl_xor(lmax, off));

    float e[16];
    float lsum = 0.f;
    #pragma unroll
    for (int q = 0; q < 4; ++q) {
        e[q * 4 + 0] = expf(v[q].x - lmax);
        e[q * 4 + 1] = expf(v[q].y - lmax);
        e[q * 4 + 2] = expf(v[q].z - lmax);
        e[q * 4 + 3] = expf(v[q].w - lmax);
        lsum += e[q * 4 + 0] + e[q * 4 + 1] + e[q * 4 + 2] + e[q * 4 + 3];
    }
    #pragma unroll
    for (int off = 1; off < 64; off <<= 1)
        lsum += __shfl_xor(lsum, off);

    float inv = 1.f / lsum;
    float thr = 1.f / (1.f + expf(-gate[h]));
    ushort* prow = (ushort*)row;   // alias — all wave reads done (shfl-synced)
    #pragma unroll
    for (int q = 0; q < 4; ++q) {
        ushort4 o;
        float p;
        p = e[q * 4 + 0] * inv; o.x = f2bf(p >= thr ? p : 0.f);
        p = e[q * 4 + 1] * inv; o.y = f2bf(p >= thr ? p : 0.f);
        p = e[q * 4 + 2] * inv; o.z = f2bf(p >= thr ? p : 0.f);
        p = e[q * 4 + 3] * inv; o.w = f2bf(p >= thr ? p : 0.f);
        ((ushort4*)prow)[lane + q * 64] = o;
    }
}

// ---------------- V^T: qkv v-part [TT,256] -> VT [256,TT] bf16 --------------
__global__ __launch_bounds__(256) void vtrans_kernel(const ushort* __restrict__ qkv,
                                                     ushort* __restrict__ VT) {
    __shared__ ushort tile[32][33];
    int s0 = blockIdx.x * 32, d0 = blockIdx.y * 32;
    int tx = threadIdx.x & 31, ty = threadIdx.x >> 5;
    for (int i = ty; i < 32; i += 8)
        tile[i][tx] = qkv[(long)(s0 + i) * QKVN + (EE + NKVH * DHEAD) + d0 + tx];
    __syncthreads();
    for (int i = ty; i < 32; i += 8)
        VT[(long)(d0 + i) * TT + s0 + tx] = tile[tx][i];
}

// ---------------- y = P @ V per head: tile 128x64, causal kmax --------------
__global__ __launch_bounds__(256) void pv_gemm(const float* __restrict__ scores,
                                               const ushort* __restrict__ VT,
                                               ushort* __restrict__ y) {
    __shared__ char lds[12288];   // A 8KB @0, B 4KB @8192
    const int tid = threadIdx.x;
    const int lane = tid & 63;
    const int w = tid >> 6;
    const int row0 = blockIdx.x * 128, h = blockIdx.y;

    const char* Pb = (const char*)(scores + (long)h * TT * TT);  // P rows: 4096B stride
    const char* Bv = (const char*)(VT + (long)(h >> 2) * DHEAD * TT);

    const char* ga[2]; char* la[2];
    #pragma unroll
    for (int r = 0; r < 2; ++r) {
        int c = r * 256 + tid;
        ga[r] = Pb + (long)(row0 + (c >> 2)) * 4096 + (c & 3) * 16;
        la[r] = lds + (r * 256 + w * 64) * 16;
    }
    const char* gb = Bv + (long)(tid >> 2) * 2048 + (tid & 3) * 16;
    char* lb = lds + 8192 + (w * 64) * 16;

    floatx4 acc[2][4];
    #pragma unroll
    for (int i = 0; i < 2; ++i)
        #pragma unroll
        for (int j = 0; j < 4; ++j) acc[i][j] = {0.f, 0.f, 0.f, 0.f};

    const int mbase = w * 32;
    const int lr = lane & 15;
    const int ko = (lane >> 4) * 16;

    const int kmax = row0 + 128;   // P[t][s]=0 for s>t, tile max t = row0+127
    for (int k0 = 0; k0 < kmax; k0 += 32) {
        #pragma unroll
        for (int r = 0; r < 2; ++r) {
            __builtin_amdgcn_global_load_lds(
                (const __attribute__((address_space(1))) void*)ga[r],
                (__attribute__((address_space(3))) void*)la[r], 16, 0, 0);
            ga[r] += 64;
        }
        __builtin_amdgcn_global_load_lds(
            (const __attribute__((address_space(1))) void*)gb,
            (__attribute__((address_space(3))) void*)lb, 16, 0, 0);
        gb += 64;
        __syncthreads();
        short8 af[2], bfr[4];
        #pragma unroll
        for (int i = 0; i < 2; ++i)
            af[i] = *(const short8*)(lds + (mbase + i * 16 + lr) * 64 + ko);
        #pragma unroll
        for (int j = 0; j < 4; ++j)
            bfr[j] = *(const short8*)(lds + 8192 + (j * 16 + lr) * 64 + ko);
        #pragma unroll
        for (int i = 0; i < 2; ++i)
            #pragma unroll
            for (int j = 0; j < 4; ++j)
                acc[i][j] = __builtin_amdgcn_mfma_f32_16x16x32_bf16(af[i], bfr[j], acc[i][j], 0, 0, 0);
        __syncthreads();
    }

    const int orow = (lane >> 4) * 4;
    const int ocol = lane & 15;
    #pragma unroll
    for (int i = 0; i < 2; ++i)
        #pragma unroll
        for (int j = 0; j < 4; ++j)
            #pragma unroll
            for (int r = 0; r < 4; ++r)
                y[(long)(row0 + mbase + i * 16 + orow + r) * EE
                  + h * DHEAD + j * 16 + ocol] = f2bf(acc[i][j][r]);
}

// ---------------- loss: combine per-colblock (max,sumexp) partials ----------
__global__ __launch_bounds__(64) void row_loss_kernel(const float* __restrict__ logits,
                                                      const float* __restrict__ lstats,
                                                      const int* __restrict__ targets,
                                                      float* __restrict__ row_loss) {
    int t = blockIdx.x;
    int lane = threadIdx.x;
    const float2* st = (const float2*)lstats + (long)t * 125;   // VV/256 blocks
    float m = -INFINITY, s = 0.f;
    for (int i = lane; i < 125; i += 64) {
        float2 v = st[i];
        float nm = fmaxf(m, v.x);
        s = s * expf(m - nm) + v.y * expf(v.x - nm);
        m = nm;
    }
    #pragma unroll
    for (int off = 1; off < 64; off <<= 1) {
        float om = __shfl_xor(m, off);
        float os = __shfl_xor(s, off);
        float nm = fmaxf(m, om);
        s = s * expf(m - nm) + os * expf(om - nm);
        m = nm;
    }
    if (lane == 0)
        row_loss[t] = logf(s) + m - logits[(long)t * VV + targets[t]];
}

__global__ __launch_bounds__(256) void final_loss_kernel(const float* __restrict__ row_loss,
                                                         float* __restrict__ out) {
    __shared__ float red[256];
    float s = 0.f;
    for (int i = threadIdx.x; i < TT; i += 256) s += row_loss[i];
    float tot = block_reduce_sum(s, red);
    if (threadIdx.x == 0) out[0] = tot * (1.f / TT);
}

// ---------------- host orchestration ----------------
extern "C" void kernel_launch(void* const* d_in, const int* in_sizes, int n_in,
                              void* d_out, int out_size, void* d_ws, size_t ws_size,
                              hipStream_t stream) {
    const float* embed = (const float*)d_in[0];
    const float* ln1_g = (const float*)d_in[1];
    const float* ln1_b = (const float*)d_in[2];
    const float* Wq    = (const float*)d_in[3];
    const float* Wk    = (const float*)d_in[4];
    const float* Wv    = (const float*)d_in[5];
    const float* Wo    = (const float*)d_in[6];
    const float* gate  = (const float*)d_in[7];
    const float* ln2_g = (const float*)d_in[8];
    const float* ln2_b = (const float*)d_in[9];
    const float* W1    = (const float*)d_in[10];
    const float* W2    = (const float*)d_in[11];
    const float* lnf_g = (const float*)d_in[12];
    const float* lnf_b = (const float*)d_in[13];
    const int*   idx   = (const int*)d_in[14];
    const int*   tgt   = (const int*)d_in[15];
    float* out = (float*)d_out;

    char* p = (char*)d_ws;
    float*  x      = (float*)p;  p += (long)TT * EE * 4;
    ushort* xn     = (ushort*)p; p += (long)TT * EE * 2;
    ushort* qkvb   = (ushort*)p; p += (long)TT * QKVN * 2;
    ushort* y      = (ushort*)p; p += (long)TT * EE * 2;
    ushort* h1     = (ushort*)p; p += (long)TT * FF * 2;
    float*  rls    = (float*)p;  p += (long)TT * 4;
    ushort* VT     = (ushort*)p; p += (long)NKVH * DHEAD * TT * 2;
    float*  scores = (float*)p;  p += (long)NH * TT * TT * 4;
    ushort* wqkvT  = (ushort*)p; p += (long)2 * QKVN * EE * 2;
    ushort* woT    = (ushort*)p; p += (long)2 * EE * EE * 2;
    ushort* w1T    = (ushort*)p; p += (long)2 * FF * EE * 2;
    ushort* w2T    = (ushort*)p; p += (long)2 * EE * FF * 2;
    ushort* embB   = (ushort*)p; p += (long)VV * EE * 2;

    // split-K partial / lstats scratch: alias scores (dead at those points)
    float* gpart = scores;

    // ---- prep: bf16 conversions / transposes ----
    convert_bf16_kernel<<<((long)VV * EE / 4 + 255) / 256, 256, 0, stream>>>(embed, embB, (long)VV * EE / 4);
    for (int l = 0; l < 2; ++l) {
        transpose_bf16_kernel<<<dim3(EE / 32, EE / 32), 256, 0, stream>>>(
            Wq + (long)l * EE * EE, wqkvT + (long)l * QKVN * EE, EE, EE);
        transpose_bf16_kernel<<<dim3(NKVH * DHEAD / 32, EE / 32), 256, 0, stream>>>(
            Wk + (long)l * EE * NKVH * DHEAD, wqkvT + (long)l * QKVN * EE + (long)EE * EE, NKVH * DHEAD, EE);
        transpose_bf16_kernel<<<dim3(NKVH * DHEAD / 32, EE / 32), 256, 0, stream>>>(
            Wv + (long)l * EE * NKVH * DHEAD, wqkvT + (long)l * QKVN * EE + (long)(EE + NKVH * DHEAD) * EE, NKVH * DHEAD, EE);
        transpose_bf16_kernel<<<dim3(EE / 32, EE / 32), 256, 0, stream>>>(
            Wo + (long)l * EE * EE, woT + (long)l * EE * EE, EE, EE);
        transpose_bf16_kernel<<<dim3(FF / 32, EE / 32), 256, 0, stream>>>(
            W1 + (long)l * EE * FF, w1T + (long)l * FF * EE, FF, EE);
        transpose_bf16_kernel<<<dim3(EE / 32, FF / 32), 256, 0, stream>>>(
            W2 + (long)l * FF * EE, w2T + (long)l * EE * FF, EE, FF);
    }

    gather_kernel<<<TT, 256, 0, stream>>>(embed, idx, x);
    ln_kernel<<<TT, 256, 0, stream>>>(x, ln1_g, ln1_b, xn);   // first ln1 (layer 0)

    for (int r = 0; r < 2; ++r) {
        for (int l = 0; l < 2; ++l) {
            // QKV projection with fused RoPE
            gemm_bf16<M_QKV><<<dim3((TT / 128) * (QKVN / 128)), 256, 0, stream>>>(
                xn, wqkvT + (long)l * QKVN * EE, qkvb, TT, QKVN, EE);
            vtrans_kernel<<<dim3(TT / 32, NKVH * DHEAD / 32), 256, 0, stream>>>(qkvb, VT);
            scores_gemm<<<dim3(TT / 128, TT / 128, NH), 256, 0, stream>>>(qkvb, scores);
            softmax_gate_kernel<<<dim3(NH, TT / 4), 256, 0, stream>>>(scores, gate + l * NH);
            pv_gemm<<<dim3(TT / 128, NH), 256, 0, stream>>>(scores, VT, y);

            // Wo: split-K=2 partials -> fused reduce + residual + LN2
            gemm_bf16<M_PART><<<dim3((TT / 128) * (EE / 128), 2), 256, 0, stream>>>(
                y, woT + (long)l * EE * EE, gpart, TT, EE, EE);
            reduce_ln_kernel<<<TT, 256, 0, stream>>>(
                gpart, x, ln2_g + l * EE, ln2_b + l * EE, xn, 2);

            // FF1 with fused GELU
            gemm_bf16<M_FF1><<<dim3((TT / 128) * (FF / 128)), 256, 0, stream>>>(
                xn, w1T + (long)l * FF * EE, h1, TT, FF, EE);

            // FF2: split-K=4 partials -> fused reduce + residual + next LN
            gemm_bf16<M_PART><<<dim3((TT / 128) * (EE / 128), 4), 256, 0, stream>>>(
                h1, w2T + (long)l * EE * FF, gpart, TT, EE, FF);
            const float* gn; const float* bn;
            if (r == 1 && l == 1) { gn = lnf_g; bn = lnf_b; }
            else { int lnx = (l == 0) ? 1 : 0; gn = ln1_g + lnx * EE; bn = ln1_b + lnx * EE; }
            reduce_ln_kernel<<<TT, 256, 0, stream>>>(gpart, x, gn, bn, xn, 4);
        }
    }

    // LM head: 256^2 counted-vmcnt kernel (xn holds lnf output)
    lmhead_gemm256<<<dim3((TT / 256) * (VV / 256)), 512, 0, stream>>>(xn, embB, out, gpart);

    row_loss_kernel<<<TT, 64, 0, stream>>>(out, gpart, tgt, rls);
    final_loss_kernel<<<1, 256, 0, stream>>>(rls, out + (long)TT * VV);
}